// Round 4
// baseline (774.920 us; speedup 1.0000x reference)
//
#include <hip/hip_runtime.h>
#include <stdint.h>

#define B_ROWS 8192
#define K_DIM 2048
#define N_DIM 2048
#define NPOP 8

typedef float f32x4 __attribute__((ext_vector_type(4)));
typedef __bf16 bf16x8 __attribute__((ext_vector_type(8)));

// group id tables: gid 0..27 = unordered pairs (a<b); gid 28..35 = slot-0 expert
// (fallback); gid 36..43 = slot-1 expert (fallback). Diagonal entries let the
// shared bias formula bias = bs_scale*(b[e1]+b[e2]) serve both paths.
__constant__ unsigned char c_pa[44] = {
  0,0,0,0,0,0,0, 1,1,1,1,1,1, 2,2,2,2,2, 3,3,3,3, 4,4,4, 5,5, 6,
  0,1,2,3,4,5,6,7, 0,1,2,3,4,5,6,7};
__constant__ unsigned char c_pb[44] = {
  1,2,3,4,5,6,7, 2,3,4,5,6,7, 3,4,5,6,7, 4,5,6,7, 5,6,7, 6,7, 7,
  0,1,2,3,4,5,6,7, 0,1,2,3,4,5,6,7};

__device__ __forceinline__ unsigned short f2bf(float f) {
  unsigned int u = __float_as_uint(f);
  u += 0x7fffu + ((u >> 16) & 1u);   // round-to-nearest-even
  return (unsigned short)(u >> 16);
}

// async global->LDS, 16B/lane; LDS dest = wave-uniform base + lane*16
__device__ __forceinline__ void glds16(const unsigned short* g, unsigned short* l) {
  __builtin_amdgcn_global_load_lds(
      (__attribute__((address_space(1))) unsigned int*)g,
      (__attribute__((address_space(3))) unsigned int*)l, 16, 0, 0);
}

// ---- fallback: W fp32 -> bf16 ----
__global__ void prep_w_kernel(const float* __restrict__ W, unsigned short* __restrict__ Wb) {
  const int n4 = NPOP * N_DIM * K_DIM / 4;
  int stride = gridDim.x * blockDim.x;
  for (int i = blockIdx.x * blockDim.x + threadIdx.x; i < n4; i += stride) {
    float4 v = reinterpret_cast<const float4*>(W)[i];
    ushort4 s;
    s.x = f2bf(v.x); s.y = f2bf(v.y); s.z = f2bf(v.z); s.w = f2bf(v.w);
    reinterpret_cast<ushort4*>(Wb)[i] = s;
  }
}

// ---- fused: Wpair[pid] = bf16( 0.5*(W[a]+W[b]) ), 0.5 combine weight folded in ----
__global__ __launch_bounds__(256) void prep_wpair_kernel(const float* __restrict__ W,
                                                         unsigned short* __restrict__ Wp) {
  const int pid = blockIdx.y;
  const float4* Wa = reinterpret_cast<const float4*>(W + (size_t)c_pa[pid] * N_DIM * K_DIM);
  const float4* Wc = reinterpret_cast<const float4*>(W + (size_t)c_pb[pid] * N_DIM * K_DIM);
  ushort4* dst = reinterpret_cast<ushort4*>(Wp + (size_t)pid * N_DIM * K_DIM);
#pragma unroll
  for (int j = 0; j < 4; ++j) {
    int i = blockIdx.x * 1024 + j * 256 + threadIdx.x;   // 1024 blk.x * 1024 f4 = 2048*2048/4
    float4 a = Wa[i], c = Wc[i];
    ushort4 s;
    s.x = f2bf(0.5f * (a.x + c.x)); s.y = f2bf(0.5f * (a.y + c.y));
    s.z = f2bf(0.5f * (a.z + c.z)); s.w = f2bf(0.5f * (a.w + c.w));
    dst[i] = s;
  }
}

// ---- selector (fp32, Ws staged in LDS) + x->bf16 conversion ----
__global__ __launch_bounds__(256) void sel_conv_x_kernel(
    const float* __restrict__ x, const float* __restrict__ Ws,
    const float* __restrict__ bs, unsigned short* __restrict__ xb,
    int* __restrict__ sel) {
  __shared__ float ws_l[NPOP * K_DIM];   // 64 KB
  const int t = threadIdx.x;
  const float4* Ws4 = reinterpret_cast<const float4*>(Ws);
  float4* wsl4 = reinterpret_cast<float4*>(ws_l);
#pragma unroll
  for (int i = 0; i < NPOP * K_DIM / 4 / 256; ++i)
    wsl4[i * 256 + t] = Ws4[i * 256 + t];
  __syncthreads();

  const int w = t >> 6, l = t & 63;
  const float4* x4 = reinterpret_cast<const float4*>(x);

  for (int rr = 0; rr < 4; ++rr) {
    int r = blockIdx.x * 16 + rr * 4 + w;
    float acc[NPOP];
#pragma unroll
    for (int p = 0; p < NPOP; ++p) acc[p] = 0.f;
#pragma unroll
    for (int j = 0; j < 8; ++j) {
      int idx = j * 256 + l * 4;
      float4 v = x4[(r * K_DIM + idx) >> 2];
      ushort4 s; s.x = f2bf(v.x); s.y = f2bf(v.y); s.z = f2bf(v.z); s.w = f2bf(v.w);
      *reinterpret_cast<ushort4*>(xb + (size_t)r * K_DIM + idx) = s;
#pragma unroll
      for (int p = 0; p < NPOP; ++p) {
        float4 wv = wsl4[(p * K_DIM + idx) >> 2];
        acc[p] += v.x * wv.x + v.y * wv.y + v.z * wv.z + v.w * wv.w;
      }
    }
#pragma unroll
    for (int off = 32; off > 0; off >>= 1)
#pragma unroll
      for (int p = 0; p < NPOP; ++p) acc[p] += __shfl_xor(acc[p], off, 64);
    if (l == 0) {
      float lg[NPOP];
#pragma unroll
      for (int p = 0; p < NPOP; ++p) lg[p] = acc[p] + bs[p];
      int p1 = 0;
#pragma unroll
      for (int p = 1; p < NPOP; ++p) if (lg[p] > lg[p1]) p1 = p;  // strict >: low idx wins ties
      int p2 = -1;
#pragma unroll
      for (int p = 0; p < NPOP; ++p) {
        if (p == p1) continue;
        if (p2 < 0 || lg[p] > lg[p2]) p2 = p;
      }
      sel[r] = p1 * 8 + p2;
    }
  }
}

// ---- build 44 row lists: 0..27 pair lists, 28..35 slot0-expert, 36..43 slot1-expert ----
__global__ __launch_bounds__(256) void build_lists_kernel(const int* __restrict__ sel,
                                                          int* __restrict__ lists,
                                                          int* __restrict__ cnt) {
  const int gid = blockIdx.x;       // 0..43
  const int t   = threadIdx.x;
  __shared__ int psum[256];
  int local[32];
  int c = 0;
#pragma unroll
  for (int i = 0; i < 32; ++i) {
    int r = i * 256 + t;
    int s = sel[r];
    int p1 = s >> 3, p2 = s & 7;
    bool match;
    if (gid < 28) {
      int a = p1 < p2 ? p1 : p2, bb = p1 < p2 ? p2 : p1;
      match = (a == c_pa[gid]) && (bb == c_pb[gid]);
    } else if (gid < 36) {
      match = (p1 == gid - 28);
    } else {
      match = (p2 == gid - 36);
    }
    if (match) local[c++] = r;
  }
  psum[t] = c;
  __syncthreads();
  for (int off = 1; off < 256; off <<= 1) {
    int v = (t >= off) ? psum[t - off] : 0;
    __syncthreads();
    psum[t] += v;
    __syncthreads();
  }
  int start = psum[t] - c;
  for (int i = 0; i < c; ++i) {
    int pos = start + i;
    if (pos < 2048) lists[gid * 2048 + pos] = local[i];
  }
  if (t == 255) cnt[gid] = psum[255] < 2048 ? psum[255] : 2048;
}

// ---- grouped GEMM, 128x128 tile, 4 waves, BK=32, XOR-swizzled LDS (conflict-free) ----
// out_row = acc_scale * (x_row @ Wstack[z]^T) + bs_scale*(b[e1]+b[e2]) ; rmw: += vs =
__global__ __launch_bounds__(256) void gemm_kernel(
    const unsigned short* __restrict__ xb,
    const unsigned short* __restrict__ Wstack,
    const float* __restrict__ bvec,
    const int* __restrict__ lists,
    const int* __restrict__ cnt,
    float* __restrict__ out,
    int gid_base, float acc_scale, float bias_scale, int rmw) {
  const int z   = blockIdx.z;
  const int gid = gid_base + z;
  const int cg  = cnt[gid];
  const int m0  = blockIdx.x * 128;
  if (m0 >= cg) return;
  const int n0 = blockIdx.y * 128;
  const int e1 = c_pa[gid], e2 = c_pb[gid];

  __shared__ __align__(16) unsigned short As[128 * 32];
  __shared__ __align__(16) unsigned short Bs[128 * 32];
  __shared__ int   sh_rows[128];
  __shared__ float sh_bias[128];

  const int t = threadIdx.x;
  const int w = t >> 6;
  const int l = t & 63;

  const int* list = lists + gid * 2048;
  if (t < 128) {
    int idx = m0 + t;
    sh_rows[t] = (idx < cg) ? list[idx] : -1;
    sh_bias[t] = bias_scale * (bvec[e1 * N_DIM + n0 + t] + bvec[e2 * N_DIM + n0 + t]);
  }
  __syncthreads();

  // staging: wave w loads A rows [32w,32w+32) and B rows [32w,32w+32); swizzle on source
  const int rg = l >> 2;
  const int ck = l & 3;
  const int tra0 = 32 * w + rg;
  const int tra1 = tra0 + 16;
  int ar0 = sh_rows[tra0]; if (ar0 < 0) ar0 = 0;
  int ar1 = sh_rows[tra1]; if (ar1 < 0) ar1 = 0;
  const unsigned short* ap0 = xb + (size_t)ar0 * K_DIM + ((ck ^ ((tra0 >> 1) & 3)) * 8);
  const unsigned short* ap1 = xb + (size_t)ar1 * K_DIM + ((ck ^ ((tra1 >> 1) & 3)) * 8);
  const unsigned short* wb0 = Wstack + (size_t)z * N_DIM * K_DIM;
  const unsigned short* bp0 = wb0 + (size_t)(n0 + tra0) * K_DIM + ((ck ^ ((tra0 >> 1) & 3)) * 8);
  const unsigned short* bp1 = wb0 + (size_t)(n0 + tra1) * K_DIM + ((ck ^ ((tra1 >> 1) & 3)) * 8);

  unsigned short* As_d0 = As + (2 * w) * 512;
  unsigned short* As_d1 = As + (2 * w + 1) * 512;
  unsigned short* Bs_d0 = Bs + (2 * w) * 512;
  unsigned short* Bs_d1 = Bs + (2 * w + 1) * 512;

  const int wm = w >> 1, wn = w & 1;
  const int lane16 = l & 15;
  const int quad   = l >> 4;

  // k-invariant swizzled fragment addresses
  const unsigned short* afp[4];
  const unsigned short* bfp[4];
#pragma unroll
  for (int mi = 0; mi < 4; ++mi) {
    int r = wm * 64 + mi * 16 + lane16;
    afp[mi] = &As[r * 32 + ((quad ^ ((r >> 1) & 3)) * 8)];
  }
#pragma unroll
  for (int ni = 0; ni < 4; ++ni) {
    int r = wn * 64 + ni * 16 + lane16;
    bfp[ni] = &Bs[r * 32 + ((quad ^ ((r >> 1) & 3)) * 8)];
  }

  f32x4 acc[4][4];
#pragma unroll
  for (int i = 0; i < 4; ++i)
#pragma unroll
    for (int j = 0; j < 4; ++j) { f32x4 zz = {0.f, 0.f, 0.f, 0.f}; acc[i][j] = zz; }

  for (int k0 = 0; k0 < K_DIM; k0 += 32) {
    glds16(ap0 + k0, As_d0);
    glds16(ap1 + k0, As_d1);
    glds16(bp0 + k0, Bs_d0);
    glds16(bp1 + k0, Bs_d1);
    __syncthreads();

    bf16x8 af[4], bf[4];
#pragma unroll
    for (int mi = 0; mi < 4; ++mi) af[mi] = *reinterpret_cast<const bf16x8*>(afp[mi]);
#pragma unroll
    for (int ni = 0; ni < 4; ++ni) bf[ni] = *reinterpret_cast<const bf16x8*>(bfp[ni]);
#pragma unroll
    for (int mi = 0; mi < 4; ++mi)
#pragma unroll
      for (int ni = 0; ni < 4; ++ni)
        acc[mi][ni] = __builtin_amdgcn_mfma_f32_16x16x32_bf16(af[mi], bf[ni], acc[mi][ni], 0, 0, 0);
    __syncthreads();
  }

  // epilogue: C/D layout col=lane&15, row=quad*4+reg
#pragma unroll
  for (int mi = 0; mi < 4; ++mi) {
#pragma unroll
    for (int i = 0; i < 4; ++i) {
      int trow = wm * 64 + mi * 16 + quad * 4 + i;
      int r = sh_rows[trow];
      if (r < 0) continue;
      float* orow = out + (size_t)r * N_DIM + n0;
#pragma unroll
      for (int ni = 0; ni < 4; ++ni) {
        int colL = wn * 64 + ni * 16 + lane16;
        float v = acc_scale * acc[mi][ni][i] + sh_bias[colL];
        if (rmw) orow[colL] += v;
        else     orow[colL] = v;
      }
    }
  }
}

extern "C" void kernel_launch(void* const* d_in, const int* in_sizes, int n_in,
                              void* d_out, int out_size, void* d_ws, size_t ws_size,
                              hipStream_t stream) {
  const float* x  = (const float*)d_in[0];
  const float* W  = (const float*)d_in[1];
  const float* b  = (const float*)d_in[2];
  const float* Ws = (const float*)d_in[3];
  const float* bs = (const float*)d_in[4];
  float* out = (float*)d_out;

  const size_t WPAIR_BYTES = (size_t)28 * N_DIM * K_DIM * 2;  // 234881024
  const size_t WB_BYTES    = (size_t)NPOP * N_DIM * K_DIM * 2; //  67108864
  const size_t XB_BYTES    = (size_t)B_ROWS * K_DIM * 2;       //  33554432
  const size_t LISTS_BYTES = (size_t)44 * 2048 * 4;
  const size_t CNT_BYTES   = 256;
  const size_t SEL_BYTES   = (size_t)B_ROWS * 4;

  bool fused = ws_size >= WPAIR_BYTES + XB_BYTES + LISTS_BYTES + CNT_BYTES + SEL_BYTES;
  size_t wbytes = fused ? WPAIR_BYTES : WB_BYTES;

  char* ws = (char*)d_ws;
  unsigned short* Wks = (unsigned short*)ws;
  unsigned short* xb  = (unsigned short*)(ws + wbytes);
  int* lists = (int*)(ws + wbytes + XB_BYTES);
  int* cnt   = (int*)(ws + wbytes + XB_BYTES + LISTS_BYTES);
  int* sel   = (int*)(ws + wbytes + XB_BYTES + LISTS_BYTES + CNT_BYTES);

  sel_conv_x_kernel<<<512, 256, 0, stream>>>(x, Ws, bs, xb, sel);
  build_lists_kernel<<<44, 256, 0, stream>>>(sel, lists, cnt);
  if (fused) {
    prep_wpair_kernel<<<dim3(1024, 28), 256, 0, stream>>>(W, Wks);
    // one pass: Wpair has 0.5 folded in; bias = 0.5*(b[e1]+b[e2])
    gemm_kernel<<<dim3(8, 16, 28), 256, 0, stream>>>(xb, Wks, b, lists, cnt, out,
                                                     0, 1.0f, 0.5f, 0);
  } else {
    prep_w_kernel<<<4096, 256, 0, stream>>>(W, Wks);
    gemm_kernel<<<dim3(16, 16, 8), 256, 0, stream>>>(xb, Wks, b, lists, cnt, out,
                                                     28, 0.5f, 0.25f, 0);
    gemm_kernel<<<dim3(16, 16, 8), 256, 0, stream>>>(xb, Wks, b, lists, cnt, out,
                                                     36, 0.5f, 0.25f, 1);
  }
}